// Round 9
// baseline (389.100 us; speedup 1.0000x reference)
//
#include <hip/hip_runtime.h>
#include <math.h>

#define D     1024
#define H     256
#define BLOW  2048
#define BTOT  4096
#define NCHUNK 64   // 4096 / 64 col chunks (per-wave) in the NT-LSE GEMM

using bf16x8 = __attribute__((ext_vector_type(8))) __bf16;
using f32x4  = __attribute__((ext_vector_type(4))) float;

// ---------------- workspace layout ----------------
// fp32 region (float units)
static const size_t OFF_SALL = 0;                 // 4096 (s_norm follows)
static const size_t OFF_SNORM= 4096;              // 4096
static const size_t OFF_EGRP = 8192;              // 4096
static const size_t OFF_ENORM= 12288;             // 4096
static const size_t OFF_P    = 16384;             // 3072: P_low, P_high, P_norm
static const size_t OFF_WV   = 19456;             // 4096: w_low, w_high, w_all, w_norm
static const size_t OFF_STATS= 23552;             // 16
static const size_t OFF_ACC  = 23568;             // 16
static const size_t OFF_DT   = 23584;             // 4096
static const size_t OFF_G    = 27680;             // 4096
static const size_t OFF_DIAG = 31776;             // 4096
static const size_t OFF_PART = 35872;             // float2[64][4096] = 524288 floats
static const size_t BF_BASE_F = 560192;           // bf16 region start (float units)
// bf16 offsets (ushort units)
static const size_t BF_ZALLN= 0;                  // [z_all(4096) ; z_normal(4096)] x 1024
static const size_t BF_ZBAR = 8388608;            // 4096 x 1024
static const size_t BF_Y    = 12582912;           // 4096 x 1024: z_all @ W0
static const size_t BF_U    = 16777216;           // 4096 x 1024: z_bar @ W1
static const size_t BF_C    = 20971520;           // 4096 x 1024
static const size_t BF_W0T  = 25165824;           // 1024 x 1024
static const size_t BF_W1T  = 26214400;           // 1024 x 1024
static const size_t BF_WA1T = 27262976;           // 256 x 1024

// ---------------- helpers ----------------
__device__ inline unsigned short f2bf(float f){
  unsigned u = __float_as_uint(f);
  u += 0x7fffu + ((u >> 16) & 1u);
  return (unsigned short)(u >> 16);
}
__device__ inline float bf2f(unsigned short u){
  return __uint_as_float(((unsigned)u) << 16);
}
__device__ inline float wave_sum(float v){
#pragma unroll
  for (int o = 32; o > 0; o >>= 1) v += __shfl_xor(v, o);
  return v;
}
__device__ inline float wave_maxf(float v){
#pragma unroll
  for (int o = 32; o > 0; o >>= 1) v = fmaxf(v, __shfl_xor(v, o));
  return v;
}
__device__ inline float block_sum(float v, float* sb){
  v = wave_sum(v);
  __syncthreads();
  if ((threadIdx.x & 63) == 0) sb[threadIdx.x >> 6] = v;
  __syncthreads();
  return sb[0] + sb[1] + sb[2] + sb[3];
}
__device__ inline float block_maxf(float v, float* sb){
  v = wave_maxf(v);
  __syncthreads();
  if ((threadIdx.x & 63) == 0) sb[threadIdx.x >> 6] = v;
  __syncthreads();
  return fmaxf(fmaxf(sb[0], sb[1]), fmaxf(sb[2], sb[3]));
}

// async global->LDS, 16 B per lane (dest = wave-uniform base + lane*16)
__device__ inline void gload16(const unsigned short* g, unsigned short* l){
  __builtin_amdgcn_global_load_lds(
      (const __attribute__((address_space(1))) unsigned int*)g,
      (__attribute__((address_space(3))) unsigned int*)l, 16, 0, 0);
}

// ---------------- fused prep: bf16 conversions + ws zeroing ----------------
__global__ __launch_bounds__(256) void k_prep(const float* __restrict__ zl,
        const float* __restrict__ zh, const float* __restrict__ znorm,
        const float* __restrict__ zbar, float* __restrict__ ws,
        unsigned short* __restrict__ zalln_bf, unsigned short* __restrict__ zbar_bf){
  int row = blockIdx.x, t = threadIdx.x, job = blockIdx.z;
  if (job == 0){
    const float4* src = (const float4*)((row < BLOW) ? (zl + (size_t)row * D)
                                                     : (zh + (size_t)(row - BLOW) * D));
    float4 v = src[t];
    *(ushort4*)(zalln_bf + (size_t)row * D + t * 4) =
        make_ushort4(f2bf(v.x), f2bf(v.y), f2bf(v.z), f2bf(v.w));
  } else if (job == 1){
    float4 v = ((const float4*)(znorm + (size_t)row * D))[t];
    *(ushort4*)(zalln_bf + (size_t)(BTOT + row) * D + t * 4) =
        make_ushort4(f2bf(v.x), f2bf(v.y), f2bf(v.z), f2bf(v.w));
    if (row < 61){
      int i = row * 256 + t;
      if (i < 8192) ws[OFF_SALL + i] = 0.f;                 // s_all + s_norm
      else if (i < 11264) ws[OFF_P + i - 8192] = 0.f;       // P_low..P_norm
      else if (i < 15360) ws[OFF_WV + i - 11264] = 0.f;     // w vectors
      else if (i < 15376) ws[OFF_ACC + i - 15360] = 0.f;    // accumulators
    }
  } else {
    float4 v = ((const float4*)(zbar + (size_t)row * D))[t];
    *(ushort4*)(zbar_bf + (size_t)row * D + t * 4) =
        make_ushort4(f2bf(v.x), f2bf(v.y), f2bf(v.z), f2bf(v.w));
  }
}

// transpose+convert: W0 -> W0T, W1 -> W1T, Wa1 -> Wa1T
__global__ __launch_bounds__(256) void k_tconv3(const float* __restrict__ W0,
        const float* __restrict__ W1, const float* __restrict__ Wa1,
        unsigned short* __restrict__ W0T, unsigned short* __restrict__ W1T,
        unsigned short* __restrict__ Wa1T){
  __shared__ float tile[32][33];
  int z = blockIdx.z;
  const float* in; unsigned short* out; int C;
  if (z == 0){ in = W0; out = W0T; C = D; }
  else if (z == 1){ in = W1; out = W1T; C = D; }
  else { if (blockIdx.x >= 8) return; in = Wa1; out = Wa1T; C = H; }
  int t = threadIdx.x;
  int lr = t >> 3;
  int lc = (t & 7) << 2;
  int gr = blockIdx.y * 32, gc = blockIdx.x * 32;
  float4 v = *(const float4*)(in + (size_t)(gr + lr) * C + gc + lc);
  tile[lr][lc + 0] = v.x; tile[lr][lc + 1] = v.y; tile[lr][lc + 2] = v.z; tile[lr][lc + 3] = v.w;
  __syncthreads();
  ushort4 o = make_ushort4(f2bf(tile[lc + 0][lr]), f2bf(tile[lc + 1][lr]),
                           f2bf(tile[lc + 2][lr]), f2bf(tile[lc + 3][lr]));
  *(ushort4*)(out + (size_t)(gc + lr) * D + gr + lc) = o;
}

// ---------------- 128x128 counted-vmcnt double-buffered core ----------------
__device__ inline void mfma_core_cv(const unsigned short* __restrict__ A, int sA,
                                    const unsigned short* __restrict__ B, int sB,
                                    int K, int row0, int col0,
                                    unsigned short* lds, f32x4 acc[4][4]){
  int t = threadIdx.x;
  int l = t & 63, w = t >> 6;
  int wrow = w >> 1, wcol = w & 1;
  int g = l >> 4, c15 = l & 15;
  const unsigned short* a0 = A + (size_t)(row0 + (t >> 2)) * sA + ((t & 3) << 3);
  const unsigned short* a1 = a0 + (size_t)64 * sA;
  const unsigned short* b0 = B + (size_t)(col0 + (t >> 2)) * sB + ((t & 3) << 3);
  const unsigned short* b1 = b0 + (size_t)64 * sB;
  int sd = w * 512;
  int abase = (wrow * 64 + c15) * 32 + g * 8;
  int bbase = 4096 + (wcol * 64 + c15) * 32 + g * 8;
  unsigned short* buf = lds;
  unsigned short* nxt = lds + 8192;
  gload16(a0, buf + sd);
  gload16(a1, buf + 2048 + sd);
  gload16(b0, buf + 4096 + sd);
  gload16(b1, buf + 6144 + sd);
  for (int kb = 0; kb < K; kb += 32){
    if (kb + 32 < K){
      gload16(a0 + kb + 32, nxt + sd);
      gload16(a1 + kb + 32, nxt + 2048 + sd);
      gload16(b0 + kb + 32, nxt + 4096 + sd);
      gload16(b1 + kb + 32, nxt + 6144 + sd);
      asm volatile("s_waitcnt vmcnt(4)" ::: "memory");
    } else {
      asm volatile("s_waitcnt vmcnt(0)" ::: "memory");
    }
    __builtin_amdgcn_sched_barrier(0);
    __builtin_amdgcn_s_barrier();
    __builtin_amdgcn_sched_barrier(0);
    bf16x8 af[4], bfr[4];
#pragma unroll
    for (int m = 0; m < 4; ++m) af[m]  = *(const bf16x8*)&buf[abase + m * 512];
#pragma unroll
    for (int n = 0; n < 4; ++n) bfr[n] = *(const bf16x8*)&buf[bbase + n * 512];
#pragma unroll
    for (int m = 0; m < 4; ++m)
#pragma unroll
      for (int n = 0; n < 4; ++n)
        acc[m][n] = __builtin_amdgcn_mfma_f32_16x16x32_bf16(af[m], bfr[n], acc[m][n], 0, 0, 0);
    __builtin_amdgcn_sched_barrier(0);
    __builtin_amdgcn_s_barrier();
    __builtin_amdgcn_sched_barrier(0);
    unsigned short* tmp = buf; buf = nxt; nxt = tmp;
  }
}

// Y/U GEMM: z=0: Ybf = z_all @ W0 ; z=1: Ubf = z_bar @ W1   (bf16 out)
__global__ __launch_bounds__(256) void k_gemm_yu(const unsigned short* __restrict__ ZALL,
        const unsigned short* __restrict__ ZBAR, const unsigned short* __restrict__ W0T,
        const unsigned short* __restrict__ W1T, unsigned short* __restrict__ Ybf,
        unsigned short* __restrict__ Ubf){
  __shared__ __align__(16) unsigned short smem[16384];
  f32x4 acc[4][4];
  f32x4 zz = {0.f, 0.f, 0.f, 0.f};
#pragma unroll
  for (int m = 0; m < 4; ++m)
#pragma unroll
    for (int n = 0; n < 4; ++n) acc[m][n] = zz;
  int row0 = blockIdx.y * 128, col0 = blockIdx.x * 128;
  const unsigned short* A = blockIdx.z ? ZBAR : ZALL;
  const unsigned short* B = blockIdx.z ? W1T : W0T;
  unsigned short* O = blockIdx.z ? Ubf : Ybf;
  mfma_core_cv(A, 1024, B, 1024, 1024, row0, col0, smem, acc);
  int t = threadIdx.x, l = t & 63, w = t >> 6, wrow = w >> 1, wcol = w & 1;
  int g = l >> 4, c15 = l & 15;
#pragma unroll
  for (int m = 0; m < 4; ++m){
    int row = row0 + wrow * 64 + m * 16 + 4 * g;
#pragma unroll
    for (int n = 0; n < 4; ++n){
      int col = col0 + wcol * 64 + n * 16 + c15;
#pragma unroll
      for (int r = 0; r < 4; ++r)
        O[(size_t)(row + r) * 1024 + col] = f2bf(acc[m][n][r]);
    }
  }
}

// scores: S[row] += sum_col tanh(z@Wa1 + ba1)[col] * Wa2[col]  (ba2 dropped: softmax-invariant)
__global__ __launch_bounds__(256) void k_scores_bf(const unsigned short* __restrict__ Zbf,
        const unsigned short* __restrict__ Wa1T, const float* __restrict__ ba1,
        const float* __restrict__ Wa2, float* __restrict__ S){
  __shared__ __align__(16) unsigned short smem[16384];
  f32x4 acc[4][4];
  f32x4 zz = {0.f, 0.f, 0.f, 0.f};
#pragma unroll
  for (int m = 0; m < 4; ++m)
#pragma unroll
    for (int n = 0; n < 4; ++n) acc[m][n] = zz;
  int row0 = blockIdx.y * 128, col0 = blockIdx.x * 128;
  mfma_core_cv(Zbf, 1024, Wa1T, 1024, 1024, row0, col0, smem, acc);
  int t = threadIdx.x, l = t & 63, w = t >> 6, wrow = w >> 1, wcol = w & 1;
  int g = l >> 4, c15 = l & 15;
#pragma unroll
  for (int m = 0; m < 4; ++m){
#pragma unroll
    for (int r = 0; r < 4; ++r){
      float v = 0.f;
#pragma unroll
      for (int n = 0; n < 4; ++n){
        int col = col0 + wcol * 64 + n * 16 + c15;
        float x = acc[m][n][r] + ba1[col];
        float e = __expf(2.f * x);
        v += (1.f - 2.f / (e + 1.f)) * Wa2[col];
      }
      v += __shfl_xor(v, 1); v += __shfl_xor(v, 2); v += __shfl_xor(v, 4); v += __shfl_xor(v, 8);
      if (c15 == 0) atomicAdd(&S[row0 + wrow * 64 + m * 16 + 4 * g + r], v);
    }
  }
}

// NT GEMM M = z_all . C^T with fused per-64col-chunk row (max,sumexp) partials + diag
__global__ __launch_bounds__(256) void k_gemm_lse(const unsigned short* __restrict__ A,
        const unsigned short* __restrict__ B, float2* __restrict__ partials,
        float* __restrict__ diagM){
  __shared__ __align__(16) unsigned short smem[16384];
  f32x4 acc[4][4];
  f32x4 zz = {0.f, 0.f, 0.f, 0.f};
#pragma unroll
  for (int m = 0; m < 4; ++m)
#pragma unroll
    for (int n = 0; n < 4; ++n) acc[m][n] = zz;
  int row0 = blockIdx.y * 128, col0 = blockIdx.x * 128;
  mfma_core_cv(A, 1024, B, 1024, 1024, row0, col0, smem, acc);
  int t = threadIdx.x, l = t & 63, w = t >> 6, wrow = w >> 1, wcol = w & 1;
  int g = l >> 4, c15 = l & 15;
  int chunk = blockIdx.x * 2 + wcol;
#pragma unroll
  for (int m = 0; m < 4; ++m){
#pragma unroll
    for (int r = 0; r < 4; ++r){
      float lm = acc[m][0][r];
#pragma unroll
      for (int n = 1; n < 4; ++n) lm = fmaxf(lm, acc[m][n][r]);
      lm = fmaxf(lm, __shfl_xor(lm, 1));
      lm = fmaxf(lm, __shfl_xor(lm, 2));
      lm = fmaxf(lm, __shfl_xor(lm, 4));
      lm = fmaxf(lm, __shfl_xor(lm, 8));
      float ls = 0.f;
#pragma unroll
      for (int n = 0; n < 4; ++n) ls += __expf(acc[m][n][r] - lm);
      ls += __shfl_xor(ls, 1); ls += __shfl_xor(ls, 2); ls += __shfl_xor(ls, 4); ls += __shfl_xor(ls, 8);
      if (c15 == 0)
        partials[(size_t)chunk * BTOT + (row0 + wrow * 64 + m * 16 + 4 * g + r)] = make_float2(lm, ls);
    }
  }
  if (blockIdx.x == blockIdx.y && wrow == wcol && ((c15 >> 2) == g)){
#pragma unroll
    for (int m = 0; m < 4; ++m)
      diagM[row0 + wrow * 64 + m * 16 + c15] = acc[m][m][c15 & 3];
  }
}

// ---------------- softmax stats (register-resident, one global pass) ----------------
// stats: 0 ml, 1 tl, 2 mh, 3 th, 4 ma, 5 ta, 6 mn, 7 tn, 8 sl, 9 sh, 10 ||P_low||^2, 11 ||P_high||^2
__global__ __launch_bounds__(256) void k_stats(const float* __restrict__ s_all,
        const float* __restrict__ s_norm, float* __restrict__ e_grp,
        float* __restrict__ e_norm, float* __restrict__ stats){
  __shared__ float sb[4];
  int t = threadIdx.x;
  float va[16], vn[16];
#pragma unroll
  for (int j = 0; j < 16; ++j) va[j] = s_all[t + 256 * j];
#pragma unroll
  for (int j = 0; j < 16; ++j) vn[j] = s_norm[t + 256 * j];
  float m = -1e30f;
#pragma unroll
  for (int j = 0; j < 8; ++j) m = fmaxf(m, va[j]);
  float ml = block_maxf(m, sb);
  m = -1e30f;
#pragma unroll
  for (int j = 8; j < 16; ++j) m = fmaxf(m, va[j]);
  float mh = block_maxf(m, sb);
  m = -1e30f;
#pragma unroll
  for (int j = 0; j < 16; ++j) m = fmaxf(m, vn[j]);
  float mn = block_maxf(m, sb);
  float ma = fmaxf(ml, mh);
  float a = 0.f;
#pragma unroll
  for (int j = 0; j < 8; ++j){ float e = __expf(va[j] - ml); e_grp[t + 256 * j] = e; a += e; }
  float tl = block_sum(a, sb);
  a = 0.f;
#pragma unroll
  for (int j = 8; j < 16; ++j){ float e = __expf(va[j] - mh); e_grp[t + 256 * j] = e; a += e; }
  float th = block_sum(a, sb);
  a = 0.f;
#pragma unroll
  for (int j = 0; j < 16; ++j){ float e = __expf(vn[j] - mn); e_norm[t + 256 * j] = e; a += e; }
  float tn = block_sum(a, sb);
  if (t == 0){
    float sl = __expf(ml - ma), sh = __expf(mh - ma);
    stats[0] = ml; stats[1] = tl; stats[2] = mh; stats[3] = th;
    stats[4] = ma; stats[5] = tl * sl + th * sh; stats[6] = mn; stats[7] = tn;
    stats[8] = sl; stats[9] = sh; stats[10] = 0.f; stats[11] = 0.f;
  }
}

// P_g[col] = sum_rows e_row * x[row][col]; groups: 0 low, 1 high, 2 norm.
__global__ __launch_bounds__(256) void k_pvec(const float* __restrict__ zl,
        const float* __restrict__ zh, const float* __restrict__ znorm,
        const float* __restrict__ e_grp, const float* __restrict__ e_norm,
        float* __restrict__ P){
  int gz = blockIdx.z;
  const float* X; const float* E; float* Pg; int nr;
  if (gz == 0){ X = zl;       E = e_grp;        Pg = P;        nr = BLOW; }
  else if (gz == 1){ X = zh;  E = e_grp + BLOW; Pg = P + 1024; nr = BLOW; }
  else { X = znorm;           E = e_norm;       Pg = P + 2048; nr = BTOT; }
  int r0 = blockIdx.y * 16;
  if (r0 >= nr) return;
  int c4 = threadIdx.x * 4;
  float4 a = make_float4(0.f, 0.f, 0.f, 0.f);
#pragma unroll 4
  for (int r = r0; r < r0 + 16; ++r){
    float e = E[r];
    float4 x = *(const float4*)(X + (size_t)r * D + c4);
    a.x = fmaf(e, x.x, a.x); a.y = fmaf(e, x.y, a.y);
    a.z = fmaf(e, x.z, a.z); a.w = fmaf(e, x.w, a.w);
  }
  atomicAdd(&Pg[c4 + 0], a.x);
  atomicAdd(&Pg[c4 + 1], a.y);
  atomicAdd(&Pg[c4 + 2], a.z);
  atomicAdd(&Pg[c4 + 3], a.w);
}

// w vectors: WV[v] = coeff_v @ W0 for v in {low, high, all, norm}; also ||P_low||^2, ||P_high||^2
__global__ __launch_bounds__(256) void k_wvecs(const float* __restrict__ P,
        float* __restrict__ stats, const float* __restrict__ W0, float* __restrict__ WV){
  int t = threadIdx.x;
  int col = blockIdx.x * 256 + t;
  int k0 = blockIdx.y * 128;
  int v = blockIdx.z;
  float sl = stats[8], sh = stats[9], itn = 1.f / stats[7];
  float a = 0.f;
  for (int k = k0; k < k0 + 128; ++k){
    float coeff = (v == 0) ? P[k]
                : (v == 1) ? P[1024 + k]
                : (v == 2) ? sl * P[k] + sh * P[1024 + k]
                : P[2048 + k] * itn;
    a = fmaf(coeff, W0[(size_t)k * D + col], a);
  }
  atomicAdd(&WV[v * 1024 + col], a);
  if (v < 2 && blockIdx.x == 0){
    __shared__ float sb[4];
    float s = 0.f;
    if (t < 128){ float pv = P[v * 1024 + k0 + t]; s = pv * pv; }
    s = block_sum(s, sb);
    if (t == 0) atomicAdd(&stats[10 + v], s);
  }
}

// fused epilogue: per row i compute C (bf16 out), pt, pn inline; dt, g, cos & hinge losses.
// C = ag*w_g + bg*y + u + 2b0 + b1 ; pt = C + aa*w_all + ba*y ; pn = C + w_norm
__global__ __launch_bounds__(256) void k_fuse(const float* __restrict__ zl,
        const float* __restrict__ zh, const float* __restrict__ zbar,
        const unsigned short* __restrict__ Ybf, const unsigned short* __restrict__ Ubf,
        const float* __restrict__ e_grp, const float* __restrict__ stats,
        const float* __restrict__ P, const float* __restrict__ WV,
        const float* __restrict__ b0, const float* __restrict__ b1,
        unsigned short* __restrict__ Cbf, float* __restrict__ dt_arr,
        float* __restrict__ g_arr, float* __restrict__ accum){
  __shared__ float sb[4];
  int i = blockIdx.x, t = threadIdx.x;
  bool lo = i < BLOW;
  const float* zrow = lo ? zl + (size_t)i * D : zh + (size_t)(i - BLOW) * D;
  float eg = e_grp[i];
  float Tg = lo ? stats[1] : stats[3];
  float sg = lo ? stats[8] : stats[9];
  float PP = lo ? stats[10] : stats[11];
  float ea = eg * sg, Ta = stats[5];
  float ag = 1.f / (Tg - eg), bg = -eg * ag;
  float aa = 1.f / (Ta - ea), ba = -ea * aa;
  const float* Pg = lo ? P : P + 1024;
  const float* wg = lo ? WV : WV + 1024;
  size_t base = (size_t)i * D;
  float4 x   = ((const float4*)zrow)[t];
  float4 zb  = ((const float4*)(zbar + base))[t];
  ushort4 y4 = *(const ushort4*)(Ybf + base + t * 4);
  ushort4 u4 = *(const ushort4*)(Ubf + base + t * 4);
  float4 y = make_float4(bf2f(y4.x), bf2f(y4.y), bf2f(y4.z), bf2f(y4.w));
  float4 u = make_float4(bf2f(u4.x), bf2f(u4.y), bf2f(u4.z), bf2f(u4.w));
  float4 pg4 = ((const float4*)Pg)[t];
  float4 wg4 = ((const float4*)wg)[t];
  float4 wa4 = ((const float4*)(WV + 2048))[t];
  float4 wn4 = ((const float4*)(WV + 3072))[t];
  float4 b04 = ((const float4*)b0)[t];
  float4 b14 = ((const float4*)b1)[t];
  float4 c;
  c.x = fmaf(ag, wg4.x, fmaf(bg, y.x, u.x + 2.f * b04.x + b14.x));
  c.y = fmaf(ag, wg4.y, fmaf(bg, y.y, u.y + 2.f * b04.y + b14.y));
  c.z = fmaf(ag, wg4.z, fmaf(bg, y.z, u.z + 2.f * b04.z + b14.z));
  c.w = fmaf(ag, wg4.w, fmaf(bg, y.w, u.w + 2.f * b04.w + b14.w));
  *(ushort4*)(Cbf + base + t * 4) = make_ushort4(f2bf(c.x), f2bf(c.y), f2bf(c.z), f2bf(c.w));
  float4 pt;
  pt.x = c.x + fmaf(aa, wa4.x, ba * y.x);
  pt.y = c.y + fmaf(aa, wa4.y, ba * y.y);
  pt.z = c.z + fmaf(aa, wa4.z, ba * y.z);
  pt.w = c.w + fmaf(aa, wa4.w, ba * y.w);
  float4 pn = make_float4(c.x + wn4.x, c.y + wn4.y, c.z + wn4.z, c.w + wn4.w);
  float nz2  = x.x*x.x + x.y*x.y + x.z*x.z + x.w*x.w;
  float zPg  = x.x*pg4.x + x.y*pg4.y + x.z*pg4.z + x.w*pg4.w;
  float nb2  = zb.x*zb.x + zb.y*zb.y + zb.z*zb.z + zb.w*zb.w;
  float dzb  = x.x*zb.x + x.y*zb.y + x.z*zb.z + x.w*zb.w;
  float dtv  = x.x*pt.x + x.y*pt.y + x.z*pt.z + x.w*pt.w;
  float npt2 = pt.x*pt.x + pt.y*pt.y + pt.z*pt.z + pt.w*pt.w;
  float dpn  = x.x*pn.x + x.y*pn.y + x.z*pn.z + x.w*pn.w;
  float npn2 = pn.x*pn.x + pn.y*pn.y + pn.z*pn.z + pn.w*pn.w;
  float gg   = x.x*wn4.x + x.y*wn4.y + x.z*wn4.z + x.w*wn4.w;
  float s_nz2  = block_sum(nz2, sb);
  float s_zPg  = block_sum(zPg, sb);
  float s_nb2  = block_sum(nb2, sb);
  float s_dzb  = block_sum(dzb, sb);
  float s_dt   = block_sum(dtv, sb);
  float s_npt2 = block_sum(npt2, sb);
  float s_dpn  = block_sum(dpn, sb);
  float s_npn2 = block_sum(npn2, sb);
  float s_g    = block_sum(gg, sb);
  if (t == 0){
    dt_arr[i] = s_dt; g_arr[i] = s_g;
    float nz = fmaxf(sqrtf(s_nz2), 1e-8f);
    // cos(z, z_hat): z_hat = ag*(P_g - eg*z)
    float dzh = ag * (s_zPg - eg * s_nz2);
    float nh2 = ag * ag * (PP - 2.f * eg * s_zPg + eg * eg * s_nz2);
    float cosA = dzh / (nz * fmaxf(sqrtf(nh2), 1e-8f));
    float cosB = s_dzb / (nz * fmaxf(sqrtf(s_nb2), 1e-8f));
    atomicAdd(&accum[0], (1.f - cosA) + (1.f - cosB));
    float ct = s_dt  / (nz * fmaxf(sqrtf(s_npt2), 1e-8f));
    float cn = s_dpn / (nz * fmaxf(sqrtf(s_npn2), 1e-8f));
    atomicAdd(&accum[1], fmaxf(0.f, 1.f - (ct - cn)));
  }
}

__global__ __launch_bounds__(256) void k_combine(const float2* __restrict__ partials,
        const float* __restrict__ diagM, const float* __restrict__ dt,
        const float* __restrict__ g, float* __restrict__ accum){
  __shared__ float sb[4];
  int i = blockIdx.x * 256 + threadIdx.x;
  float m = -1e30f, S = 0.f;
  for (int c = 0; c < NCHUNK; ++c){
    float2 p = partials[(size_t)c * BTOT + i];
    float nm = fmaxf(m, p.x);
    S = S * __expf(m - nm) + p.y * __expf(p.x - nm);
    m = nm;
  }
  float vold = diagM[i];
  float vnew = dt[i] - g[i];
  float nm = fmaxf(m, vnew);
  float S2 = S * __expf(m - nm) - __expf(vold - nm) + __expf(vnew - nm);
  float lse = g[i] + nm + logf(S2);
  float contrib = lse - dt[i];
  float tot = block_sum(contrib, sb);
  if (threadIdx.x == 0) atomicAdd(&accum[2], tot);
}

__global__ void k_final(const float* __restrict__ accum, float* __restrict__ out){
  out[0] = accum[2] / (float)BTOT;
  out[1] = (accum[0] + accum[1]) / (float)BTOT;
}

// ---------------- launch ----------------
extern "C" void kernel_launch(void* const* d_in, const int* in_sizes, int n_in,
                              void* d_out, int out_size, void* d_ws, size_t ws_size,
                              hipStream_t stream){
  const float* z_low    = (const float*)d_in[0];
  const float* z_high   = (const float*)d_in[1];
  const float* z_bar    = (const float*)d_in[2];
  const float* z_normal = (const float*)d_in[3];
  const float* Wa1      = (const float*)d_in[4];
  const float* ba1      = (const float*)d_in[5];
  const float* Wa2      = (const float*)d_in[6];
  const float* ba2      = (const float*)d_in[7];   // dropped: softmax shift-invariant
  const float* W0       = (const float*)d_in[8];
  const float* b0       = (const float*)d_in[9];
  const float* W1       = (const float*)d_in[10];
  const float* b1       = (const float*)d_in[11];
  float* ws = (float*)d_ws;
  unsigned short* bw = (unsigned short*)(ws + BF_BASE_F);
  float* out = (float*)d_out;
  (void)ba2;

  k_prep<<<dim3(BTOT, 1, 3), dim3(256), 0, stream>>>(z_low, z_high, z_normal, z_bar,
      ws, bw + BF_ZALLN, bw + BF_ZBAR);
  k_tconv3<<<dim3(32, 32, 3), dim3(256), 0, stream>>>(W0, W1, Wa1,
      bw + BF_W0T, bw + BF_W1T, bw + BF_WA1T);

  // Y = z_all@W0, U = z_bar@W1 (independent of softmax chain)
  k_gemm_yu<<<dim3(8, 32, 2), dim3(256), 0, stream>>>(bw + BF_ZALLN, bw + BF_ZBAR,
      bw + BF_W0T, bw + BF_W1T, bw + BF_Y, bw + BF_U);

  // scores over [z_all ; z_normal] (M = 8192)
  k_scores_bf<<<dim3(2, 64), dim3(256), 0, stream>>>(bw + BF_ZALLN, bw + BF_WA1T,
      ba1, Wa2, ws + OFF_SALL);

  k_stats<<<dim3(1), dim3(256), 0, stream>>>(ws + OFF_SALL, ws + OFF_SNORM,
      ws + OFF_EGRP, ws + OFF_ENORM, ws + OFF_STATS);

  k_pvec<<<dim3(1, 256, 3), dim3(256), 0, stream>>>(z_low, z_high, z_normal,
      ws + OFF_EGRP, ws + OFF_ENORM, ws + OFF_P);

  k_wvecs<<<dim3(4, 8, 4), dim3(256), 0, stream>>>(ws + OFF_P, ws + OFF_STATS,
      W0, ws + OFF_WV);

  k_fuse<<<dim3(BTOT), dim3(256), 0, stream>>>(z_low, z_high, z_bar,
      bw + BF_Y, bw + BF_U, ws + OFF_EGRP, ws + OFF_STATS, ws + OFF_P, ws + OFF_WV,
      b0, b1, bw + BF_C, ws + OFF_DT, ws + OFF_G, ws + OFF_ACC);

  k_gemm_lse<<<dim3(32, 32), dim3(256), 0, stream>>>(bw + BF_ZALLN, bw + BF_C,
      (float2*)(ws + OFF_PART), ws + OFF_DIAG);

  k_combine<<<dim3(16), dim3(256), 0, stream>>>((const float2*)(ws + OFF_PART),
      ws + OFF_DIAG, ws + OFF_DT, ws + OFF_G, ws + OFF_ACC);

  k_final<<<dim3(1), dim3(1), 0, stream>>>(ws + OFF_ACC, out);
}